// Round 1
// baseline (628.965 us; speedup 1.0000x reference)
//
#include <hip/hip_runtime.h>

#define N_NODES 50000
#define N_EDGES 800000
#define D 128
#define N_GRAPHS 256
#define N_CLASSES 16

typedef unsigned short ushort_t;
typedef unsigned int uint_t;

__device__ __forceinline__ float bf2f(uint_t u) {
  return __uint_as_float(u << 16);
}
__device__ __forceinline__ uint_t f2bf(float f) {
  uint_t x = __float_as_uint(f);
  return (x + 0x7fffu + ((x >> 16) & 1u)) >> 16;
}

// ---- degree histogram (in-degree over dst) ----
__global__ void k_hist(const int* __restrict__ ei, int* __restrict__ deg) {
  int e = blockIdx.x * blockDim.x + threadIdx.x;
  if (e < N_EDGES) atomicAdd(&deg[ei[N_EDGES + e]], 1);
}

// ---- dinv = rsqrt(deg + 1)  (+1 = self-loop) ----
__global__ void k_dinv(const int* __restrict__ deg, float* __restrict__ dinv) {
  int n = blockIdx.x * blockDim.x + threadIdx.x;
  if (n < N_NODES) dinv[n] = rsqrtf((float)(deg[n] + 1));
}

// ---- exclusive prefix scan over deg -> offsets, cursor ----
__global__ __launch_bounds__(1024) void k_scan(const int* __restrict__ deg,
                                               int* __restrict__ offs,
                                               int* __restrict__ cursor) {
  __shared__ int part[1024];
  int t = threadIdx.x;
  const int CH = (N_NODES + 1023) / 1024;  // 49
  int base = t * CH;
  int s = 0;
  for (int i = 0; i < CH; ++i) {
    int idx = base + i;
    if (idx < N_NODES) s += deg[idx];
  }
  part[t] = s;
  __syncthreads();
  for (int o = 1; o < 1024; o <<= 1) {
    int v = part[t];
    int add = (t >= o) ? part[t - o] : 0;
    __syncthreads();
    part[t] = v + add;
    __syncthreads();
  }
  int run = (t == 0) ? 0 : part[t - 1];
  for (int i = 0; i < CH; ++i) {
    int idx = base + i;
    if (idx < N_NODES) {
      offs[idx] = run;
      cursor[idx] = run;
      run += deg[idx];
    }
  }
  if (t == 1023) offs[N_NODES] = part[1023];
}

// ---- counting-sort edges by dst into CSR (src, weight) ----
__global__ void k_csr(const int* __restrict__ ei, const float* __restrict__ dinv,
                      int* __restrict__ cursor, int2* __restrict__ csr) {
  int e = blockIdx.x * blockDim.x + threadIdx.x;
  if (e >= N_EDGES) return;
  int s = ei[e];
  int d = ei[N_EDGES + e];
  int pos = atomicAdd(&cursor[d], 1);
  float w = dinv[s] * dinv[d];
  csr[pos] = make_int2(s, __float_as_int(w));
}

// ---- GEMM: [N x 128] @ [128 x 128] -> bf16 out. W staged in LDS. ----
template <typename TIN>
__global__ __launch_bounds__(256) void k_gemm(const TIN* __restrict__ A,
                                              const float* __restrict__ W,
                                              ushort_t* __restrict__ Out) {
  __shared__ float Asm[64][128];   // 32 KB
  __shared__ float Wsm[128][128];  // 64 KB
  int t = threadIdx.x;
  const float4* W4 = (const float4*)W;
  float4* Ws4 = (float4*)&Wsm[0][0];
#pragma unroll
  for (int i = 0; i < 16; ++i) Ws4[t + 256 * i] = W4[t + 256 * i];
  int row0 = blockIdx.x * 64;
  if constexpr (sizeof(TIN) == 4) {  // fp32 input
    const float4* A4 = (const float4*)(A + (size_t)row0 * D);
    float4* As4 = (float4*)&Asm[0][0];
#pragma unroll
    for (int i = 0; i < 8; ++i) {
      int idx = t + 256 * i;  // float4 index, 32 per row
      int r = idx >> 5;
      float4 v = make_float4(0.f, 0.f, 0.f, 0.f);
      if (row0 + r < N_NODES) v = A4[idx];
      As4[idx] = v;
    }
  } else {  // bf16 input
    const uint4* A8 = (const uint4*)(A + (size_t)row0 * D);
#pragma unroll
    for (int i = 0; i < 4; ++i) {
      int idx = t + 256 * i;  // uint4 (8 bf16) index, 16 per row
      int r = idx >> 4;
      uint4 v = make_uint4(0, 0, 0, 0);
      if (row0 + r < N_NODES) v = A8[idx];
      float* dst = &Asm[0][0] + (size_t)idx * 8;
      dst[0] = bf2f(v.x & 0xffffu); dst[1] = bf2f(v.x >> 16);
      dst[2] = bf2f(v.y & 0xffffu); dst[3] = bf2f(v.y >> 16);
      dst[4] = bf2f(v.z & 0xffffu); dst[5] = bf2f(v.z >> 16);
      dst[6] = bf2f(v.w & 0xffffu); dst[7] = bf2f(v.w >> 16);
    }
  }
  __syncthreads();
  int tr = t >> 5, tc = t & 31;  // 8 row-groups x 32 col-threads
  float acc[8][4] = {};
  for (int k = 0; k < D; ++k) {
    float4 w = *(const float4*)&Wsm[k][tc * 4];
#pragma unroll
    for (int i = 0; i < 8; ++i) {
      float a = Asm[tr * 8 + i][k];
      acc[i][0] = fmaf(a, w.x, acc[i][0]);
      acc[i][1] = fmaf(a, w.y, acc[i][1]);
      acc[i][2] = fmaf(a, w.z, acc[i][2]);
      acc[i][3] = fmaf(a, w.w, acc[i][3]);
    }
  }
#pragma unroll
  for (int i = 0; i < 8; ++i) {
    int r = row0 + tr * 8 + i;
    if (r < N_NODES) {
      uint_t lo = f2bf(acc[i][0]) | (f2bf(acc[i][1]) << 16);
      uint_t hi = f2bf(acc[i][2]) | (f2bf(acc[i][3]) << 16);
      *(uint2*)(Out + (size_t)r * D + tc * 4) = make_uint2(lo, hi);
    }
  }
}

// ---- aggregation: one wave per node; lane owns 2 dims ----
// MODE 0: out = relu(agg + bias) -> bf16 ; MODE 1: out = agg + bias -> f32
template <int MODE>
__global__ __launch_bounds__(256) void k_agg(const ushort_t* __restrict__ h,
                                             const int2* __restrict__ csr,
                                             const int* __restrict__ offs,
                                             const float* __restrict__ dinv,
                                             const float* __restrict__ bias,
                                             ushort_t* __restrict__ obf,
                                             float* __restrict__ of) {
  int wv = threadIdx.x >> 6;
  int lane = threadIdx.x & 63;
  int node = blockIdx.x * 4 + wv;
  if (node >= N_NODES) return;
  int beg = offs[node], end = offs[node + 1];
  int d0 = lane * 2;
  float a0 = 0.f, a1 = 0.f;
  for (int base = beg; base < end; base += 64) {
    int cnt = min(64, end - base);
    int2 le = make_int2(0, 0);
    if (lane < cnt) le = csr[base + lane];
    for (int j = 0; j < cnt; ++j) {
      int s = __shfl(le.x, j);
      float w = __int_as_float(__shfl(le.y, j));
      uint_t u = *(const uint_t*)(h + (size_t)s * D + d0);
      a0 = fmaf(w, bf2f(u & 0xffffu), a0);
      a1 = fmaf(w, bf2f(u >> 16), a1);
    }
  }
  // self-loop: weight = dinv[n]^2
  float dn = dinv[node];
  float wsl = dn * dn;
  uint_t u = *(const uint_t*)(h + (size_t)node * D + d0);
  a0 = fmaf(wsl, bf2f(u & 0xffffu), a0);
  a1 = fmaf(wsl, bf2f(u >> 16), a1);
  a0 += bias[d0];
  a1 += bias[d0 + 1];
  if (MODE == 0) {
    a0 = fmaxf(a0, 0.f);
    a1 = fmaxf(a1, 0.f);
    *(uint_t*)(obf + (size_t)node * D + d0) = f2bf(a0) | (f2bf(a1) << 16);
  } else {
    *(float2*)(of + (size_t)node * D + d0) = make_float2(a0, a1);
  }
}

// ---- per-graph node counts ----
__global__ void k_cnt(const int* __restrict__ batch, int* __restrict__ cnts) {
  int i = blockIdx.x * blockDim.x + threadIdx.x;
  if (i < N_NODES) atomicAdd(&cnts[batch[i]], 1);
}

// ---- pooled sums, exploiting sorted batch (run-length accumulate) ----
__global__ __launch_bounds__(128) void k_pool(const float* __restrict__ h,
                                              const int* __restrict__ batch,
                                              float* __restrict__ sums) {
  __shared__ int bsm[256];
  int n0 = blockIdx.x * 256;
  int t = threadIdx.x;
  int cnt = min(256, N_NODES - n0);
  for (int i = t; i < cnt; i += 128) bsm[i] = batch[n0 + i];
  __syncthreads();
  float acc = 0.f;
  int gcur = bsm[0];
  for (int i = 0; i < cnt; ++i) {
    int g = bsm[i];
    if (g != gcur) {
      atomicAdd(&sums[gcur * D + t], acc);
      acc = 0.f;
      gcur = g;
    }
    acc += h[(size_t)(n0 + i) * D + t];
  }
  atomicAdd(&sums[gcur * D + t], acc);
}

// ---- mean + final linear head ----
__global__ __launch_bounds__(128) void k_final(const float* __restrict__ sums,
                                               const int* __restrict__ cnts,
                                               const float* __restrict__ Wc,
                                               const float* __restrict__ bc,
                                               float* __restrict__ out) {
  __shared__ float p[128];
  int g = blockIdx.x;
  int t = threadIdx.x;
  float c = (float)max(cnts[g], 1);
  p[t] = sums[g * D + t] / c;
  __syncthreads();
  if (t < N_CLASSES) {
    float acc = bc[t];
    for (int k = 0; k < D; ++k) acc = fmaf(p[k], Wc[k * N_CLASSES + t], acc);
    out[g * N_CLASSES + t] = acc;
  }
}

extern "C" void kernel_launch(void* const* d_in, const int* in_sizes, int n_in,
                              void* d_out, int out_size, void* d_ws, size_t ws_size,
                              hipStream_t stream) {
  const float* x = (const float*)d_in[0];
  const int* ei = (const int*)d_in[1];
  const int* batch = (const int*)d_in[2];
  const float* W1 = (const float*)d_in[3];
  const float* b1 = (const float*)d_in[4];
  const float* W2 = (const float*)d_in[5];
  const float* b2 = (const float*)d_in[6];
  const float* Wc = (const float*)d_in[7];
  const float* bc = (const float*)d_in[8];
  float* out = (float*)d_out;

  char* ws = (char*)d_ws;
  size_t off = 0;
  auto alloc = [&](size_t bytes) -> void* {
    void* p = (void*)(ws + off);
    off += (bytes + 255) & ~(size_t)255;
    return p;
  };
  int* deg = (int*)alloc((size_t)N_NODES * 4);
  int* cursor = (int*)alloc((size_t)N_NODES * 4);
  int* offs = (int*)alloc((size_t)(N_NODES + 1) * 4);
  float* dinv = (float*)alloc((size_t)N_NODES * 4);
  int2* csr = (int2*)alloc((size_t)N_EDGES * 8);
  ushort_t* hbuf = (ushort_t*)alloc((size_t)N_NODES * D * 2);  // h1 then h2 (bf16)
  ushort_t* x2 = (ushort_t*)alloc((size_t)N_NODES * D * 2);    // relu(conv1) bf16
  float* h2f = (float*)alloc((size_t)N_NODES * D * 4);         // conv2 out f32
  float* sums = (float*)alloc((size_t)N_GRAPHS * D * 4);
  int* cnts = (int*)alloc((size_t)N_GRAPHS * 4);

  hipMemsetAsync(deg, 0, (size_t)N_NODES * 4, stream);
  hipMemsetAsync(sums, 0, (size_t)N_GRAPHS * D * 4, stream);
  hipMemsetAsync(cnts, 0, (size_t)N_GRAPHS * 4, stream);

  k_hist<<<(N_EDGES + 255) / 256, 256, 0, stream>>>(ei, deg);
  k_dinv<<<(N_NODES + 255) / 256, 256, 0, stream>>>(deg, dinv);
  k_scan<<<1, 1024, 0, stream>>>(deg, offs, cursor);
  k_csr<<<(N_EDGES + 255) / 256, 256, 0, stream>>>(ei, dinv, cursor, csr);

  k_gemm<float><<<(N_NODES + 63) / 64, 256, 0, stream>>>(x, W1, hbuf);
  k_agg<0><<<(N_NODES + 3) / 4, 256, 0, stream>>>(hbuf, csr, offs, dinv, b1, x2, nullptr);
  k_gemm<ushort_t><<<(N_NODES + 63) / 64, 256, 0, stream>>>(x2, W2, hbuf);
  k_agg<1><<<(N_NODES + 3) / 4, 256, 0, stream>>>(hbuf, csr, offs, dinv, b2, nullptr, h2f);

  k_cnt<<<(N_NODES + 255) / 256, 256, 0, stream>>>(batch, cnts);
  k_pool<<<(N_NODES + 255) / 256, 128, 0, stream>>>(h2f, batch, sums);
  k_final<<<N_GRAPHS, 128, 0, stream>>>(sums, cnts, Wc, bc, out);
}

// Round 2
// 477.717 us; speedup vs baseline: 1.3166x; 1.3166x over previous
//
#include <hip/hip_runtime.h>

#define N_NODES 50000
#define N_EDGES 800000
#define D 128
#define N_GRAPHS 256
#define N_CLASSES 16
#define NB_SCAN ((N_NODES + 255) / 256)  // 196

typedef unsigned short ushort_t;
typedef unsigned int uint_t;

__device__ __forceinline__ float bf2f(uint_t u) {
  return __uint_as_float(u << 16);
}
__device__ __forceinline__ uint_t f2bf(float f) {
  uint_t x = __float_as_uint(f);
  return (x + 0x7fffu + ((x >> 16) & 1u)) >> 16;
}

// ---- degree histogram (in-degree over dst) ----
__global__ void k_hist(const int* __restrict__ ei, int* __restrict__ deg) {
  int e = blockIdx.x * blockDim.x + threadIdx.x;
  if (e < N_EDGES) atomicAdd(&deg[ei[N_EDGES + e]], 1);
}

// ---- dinv = rsqrt(deg + 1)  (+1 = self-loop) ----
__global__ void k_dinv(const int* __restrict__ deg, float* __restrict__ dinv) {
  int n = blockIdx.x * blockDim.x + threadIdx.x;
  if (n < N_NODES) dinv[n] = rsqrtf((float)(deg[n] + 1));
}

// ---- hierarchical scan: block sums ----
__global__ __launch_bounds__(256) void k_bsum(const int* __restrict__ deg,
                                              int* __restrict__ bsum) {
  int t = threadIdx.x;
  int i = blockIdx.x * 256 + t;
  int d = (i < N_NODES) ? deg[i] : 0;
#pragma unroll
  for (int o = 1; o < 64; o <<= 1) d += __shfl_xor(d, o);
  __shared__ int ws[4];
  if ((t & 63) == 0) ws[t >> 6] = d;
  __syncthreads();
  if (t == 0) bsum[blockIdx.x] = ws[0] + ws[1] + ws[2] + ws[3];
}

// ---- scan the 196 partials (1 block) ----
__global__ __launch_bounds__(256) void k_spart(const int* __restrict__ bsum,
                                               int* __restrict__ bpre,
                                               int* __restrict__ offs) {
  int t = threadIdx.x;
  int lane = t & 63, wid = t >> 6;
  int d = (t < NB_SCAN) ? bsum[t] : 0;
  int v = d;
#pragma unroll
  for (int o = 1; o < 64; o <<= 1) {
    int u = __shfl_up(v, o);
    if (lane >= o) v += u;
  }
  __shared__ int ws[4];
  if (lane == 63) ws[wid] = v;
  __syncthreads();
  int add = 0;
  for (int w = 0; w < wid; ++w) add += ws[w];
  int excl = v - d + add;
  if (t < NB_SCAN) bpre[t] = excl;
  if (t == NB_SCAN - 1) offs[N_NODES] = excl + d;
}

// ---- fill offsets/cursor with in-block wave scan ----
__global__ __launch_bounds__(256) void k_fill(const int* __restrict__ deg,
                                              const int* __restrict__ bpre,
                                              int* __restrict__ offs,
                                              int* __restrict__ cursor) {
  int t = threadIdx.x;
  int i = blockIdx.x * 256 + t;
  int d = (i < N_NODES) ? deg[i] : 0;
  int lane = t & 63, wid = t >> 6;
  int v = d;
#pragma unroll
  for (int o = 1; o < 64; o <<= 1) {
    int u = __shfl_up(v, o);
    if (lane >= o) v += u;
  }
  __shared__ int ws[4];
  if (lane == 63) ws[wid] = v;
  __syncthreads();
  int add = bpre[blockIdx.x];
  for (int w = 0; w < wid; ++w) add += ws[w];
  int excl = v - d + add;
  if (i < N_NODES) {
    offs[i] = excl;
    cursor[i] = excl;
  }
}

// ---- counting-sort edges by dst into CSR (src, weight) ----
__global__ void k_csr(const int* __restrict__ ei, const float* __restrict__ dinv,
                      int* __restrict__ cursor, int2* __restrict__ csr) {
  int e = blockIdx.x * blockDim.x + threadIdx.x;
  if (e >= N_EDGES) return;
  int s = ei[e];
  int d = ei[N_EDGES + e];
  int pos = atomicAdd(&cursor[d], 1);
  float w = dinv[s] * dinv[d];
  csr[pos] = make_int2(s, __float_as_int(w));
}

// ---- GEMM: [N x 128] @ [128 x 128] -> bf16 out. W staged in LDS. ----
template <typename TIN>
__global__ __launch_bounds__(256) void k_gemm(const TIN* __restrict__ A,
                                              const float* __restrict__ W,
                                              ushort_t* __restrict__ Out) {
  __shared__ float Asm[64][128];   // 32 KB
  __shared__ float Wsm[128][128];  // 64 KB
  int t = threadIdx.x;
  const float4* W4 = (const float4*)W;
  float4* Ws4 = (float4*)&Wsm[0][0];
#pragma unroll
  for (int i = 0; i < 16; ++i) Ws4[t + 256 * i] = W4[t + 256 * i];
  int row0 = blockIdx.x * 64;
  if constexpr (sizeof(TIN) == 4) {  // fp32 input
    const float4* A4 = (const float4*)(A + (size_t)row0 * D);
    float4* As4 = (float4*)&Asm[0][0];
#pragma unroll
    for (int i = 0; i < 8; ++i) {
      int idx = t + 256 * i;  // float4 index, 32 per row
      int r = idx >> 5;
      float4 v = make_float4(0.f, 0.f, 0.f, 0.f);
      if (row0 + r < N_NODES) v = A4[idx];
      As4[idx] = v;
    }
  } else {  // bf16 input
    const uint4* A8 = (const uint4*)(A + (size_t)row0 * D);
#pragma unroll
    for (int i = 0; i < 4; ++i) {
      int idx = t + 256 * i;  // uint4 (8 bf16) index, 16 per row
      int r = idx >> 4;
      uint4 v = make_uint4(0, 0, 0, 0);
      if (row0 + r < N_NODES) v = A8[idx];
      float* dst = &Asm[0][0] + (size_t)idx * 8;
      dst[0] = bf2f(v.x & 0xffffu); dst[1] = bf2f(v.x >> 16);
      dst[2] = bf2f(v.y & 0xffffu); dst[3] = bf2f(v.y >> 16);
      dst[4] = bf2f(v.z & 0xffffu); dst[5] = bf2f(v.z >> 16);
      dst[6] = bf2f(v.w & 0xffffu); dst[7] = bf2f(v.w >> 16);
    }
  }
  __syncthreads();
  int tr = t >> 5, tc = t & 31;  // 8 row-groups x 32 col-threads
  float acc[8][4] = {};
  for (int k = 0; k < D; ++k) {
    float4 w = *(const float4*)&Wsm[k][tc * 4];
#pragma unroll
    for (int i = 0; i < 8; ++i) {
      float a = Asm[tr * 8 + i][k];
      acc[i][0] = fmaf(a, w.x, acc[i][0]);
      acc[i][1] = fmaf(a, w.y, acc[i][1]);
      acc[i][2] = fmaf(a, w.z, acc[i][2]);
      acc[i][3] = fmaf(a, w.w, acc[i][3]);
    }
  }
#pragma unroll
  for (int i = 0; i < 8; ++i) {
    int r = row0 + tr * 8 + i;
    if (r < N_NODES) {
      uint_t lo = f2bf(acc[i][0]) | (f2bf(acc[i][1]) << 16);
      uint_t hi = f2bf(acc[i][2]) | (f2bf(acc[i][3]) << 16);
      *(uint2*)(Out + (size_t)r * D + tc * 4) = make_uint2(lo, hi);
    }
  }
}

// ---- aggregation: one wave per node; 4 edge-groups x 16 lanes; lane owns 8 dims
// MODE 0: out = relu(agg + bias) -> bf16 ; MODE 1: out = agg + bias -> f32
template <int MODE>
__global__ __launch_bounds__(256) void k_agg(const ushort_t* __restrict__ h,
                                             const int2* __restrict__ csr,
                                             const int* __restrict__ offs,
                                             const float* __restrict__ dinv,
                                             const float* __restrict__ bias,
                                             ushort_t* __restrict__ obf,
                                             float* __restrict__ of) {
  int wv = threadIdx.x >> 6;
  int lane = threadIdx.x & 63;
  int node = blockIdx.x * 4 + wv;
  if (node >= N_NODES) return;
  int grp = lane >> 4;   // 0..3: which edge of the chunk
  int gl = lane & 15;    // lane in group
  int d0 = gl * 8;       // dims [d0, d0+8)
  int beg = offs[node], end = offs[node + 1];
  float acc[8] = {0.f, 0.f, 0.f, 0.f, 0.f, 0.f, 0.f, 0.f};
  for (int base = beg + grp; base < end; base += 4) {
    int2 e = csr[base];  // all 16 lanes in group: same addr (broadcast)
    float w = __int_as_float(e.y);
    uint4 v = *(const uint4*)(h + (size_t)e.x * D + d0);
    acc[0] = fmaf(w, bf2f(v.x & 0xffffu), acc[0]);
    acc[1] = fmaf(w, bf2f(v.x >> 16), acc[1]);
    acc[2] = fmaf(w, bf2f(v.y & 0xffffu), acc[2]);
    acc[3] = fmaf(w, bf2f(v.y >> 16), acc[3]);
    acc[4] = fmaf(w, bf2f(v.z & 0xffffu), acc[4]);
    acc[5] = fmaf(w, bf2f(v.z >> 16), acc[5]);
    acc[6] = fmaf(w, bf2f(v.w & 0xffffu), acc[6]);
    acc[7] = fmaf(w, bf2f(v.w >> 16), acc[7]);
  }
  // butterfly-reduce the 4 edge-groups (lanes gl, gl+16, gl+32, gl+48)
#pragma unroll
  for (int m = 16; m <= 32; m <<= 1) {
#pragma unroll
    for (int i = 0; i < 8; ++i) acc[i] += __shfl_xor(acc[i], m);
  }
  if (grp == 0) {
    // self-loop: weight = dinv[n]^2
    float dn = dinv[node];
    float wsl = dn * dn;
    uint4 v = *(const uint4*)(h + (size_t)node * D + d0);
    acc[0] = fmaf(wsl, bf2f(v.x & 0xffffu), acc[0]);
    acc[1] = fmaf(wsl, bf2f(v.x >> 16), acc[1]);
    acc[2] = fmaf(wsl, bf2f(v.y & 0xffffu), acc[2]);
    acc[3] = fmaf(wsl, bf2f(v.y >> 16), acc[3]);
    acc[4] = fmaf(wsl, bf2f(v.z & 0xffffu), acc[4]);
    acc[5] = fmaf(wsl, bf2f(v.z >> 16), acc[5]);
    acc[6] = fmaf(wsl, bf2f(v.w & 0xffffu), acc[6]);
    acc[7] = fmaf(wsl, bf2f(v.w >> 16), acc[7]);
    float4 blo = *(const float4*)(bias + d0);
    float4 bhi = *(const float4*)(bias + d0 + 4);
    acc[0] += blo.x; acc[1] += blo.y; acc[2] += blo.z; acc[3] += blo.w;
    acc[4] += bhi.x; acc[5] += bhi.y; acc[6] += bhi.z; acc[7] += bhi.w;
    if (MODE == 0) {
#pragma unroll
      for (int i = 0; i < 8; ++i) acc[i] = fmaxf(acc[i], 0.f);
      uint4 o;
      o.x = f2bf(acc[0]) | (f2bf(acc[1]) << 16);
      o.y = f2bf(acc[2]) | (f2bf(acc[3]) << 16);
      o.z = f2bf(acc[4]) | (f2bf(acc[5]) << 16);
      o.w = f2bf(acc[6]) | (f2bf(acc[7]) << 16);
      *(uint4*)(obf + (size_t)node * D + d0) = o;
    } else {
      *(float4*)(of + (size_t)node * D + d0) = make_float4(acc[0], acc[1], acc[2], acc[3]);
      *(float4*)(of + (size_t)node * D + d0 + 4) = make_float4(acc[4], acc[5], acc[6], acc[7]);
    }
  }
}

// ---- per-graph node counts ----
__global__ void k_cnt(const int* __restrict__ batch, int* __restrict__ cnts) {
  int i = blockIdx.x * blockDim.x + threadIdx.x;
  if (i < N_NODES) atomicAdd(&cnts[batch[i]], 1);
}

// ---- pooled sums, exploiting sorted batch (run-length accumulate) ----
__global__ __launch_bounds__(128) void k_pool(const float* __restrict__ h,
                                              const int* __restrict__ batch,
                                              float* __restrict__ sums) {
  __shared__ int bsm[256];
  int n0 = blockIdx.x * 256;
  int t = threadIdx.x;
  int cnt = min(256, N_NODES - n0);
  for (int i = t; i < cnt; i += 128) bsm[i] = batch[n0 + i];
  __syncthreads();
  float acc = 0.f;
  int gcur = bsm[0];
  for (int i = 0; i < cnt; ++i) {
    int g = bsm[i];
    if (g != gcur) {
      atomicAdd(&sums[gcur * D + t], acc);
      acc = 0.f;
      gcur = g;
    }
    acc += h[(size_t)(n0 + i) * D + t];
  }
  atomicAdd(&sums[gcur * D + t], acc);
}

// ---- mean + final linear head ----
__global__ __launch_bounds__(128) void k_final(const float* __restrict__ sums,
                                               const int* __restrict__ cnts,
                                               const float* __restrict__ Wc,
                                               const float* __restrict__ bc,
                                               float* __restrict__ out) {
  __shared__ float p[128];
  int g = blockIdx.x;
  int t = threadIdx.x;
  float c = (float)max(cnts[g], 1);
  p[t] = sums[g * D + t] / c;
  __syncthreads();
  if (t < N_CLASSES) {
    float acc = bc[t];
    for (int k = 0; k < D; ++k) acc = fmaf(p[k], Wc[k * N_CLASSES + t], acc);
    out[g * N_CLASSES + t] = acc;
  }
}

extern "C" void kernel_launch(void* const* d_in, const int* in_sizes, int n_in,
                              void* d_out, int out_size, void* d_ws, size_t ws_size,
                              hipStream_t stream) {
  const float* x = (const float*)d_in[0];
  const int* ei = (const int*)d_in[1];
  const int* batch = (const int*)d_in[2];
  const float* W1 = (const float*)d_in[3];
  const float* b1 = (const float*)d_in[4];
  const float* W2 = (const float*)d_in[5];
  const float* b2 = (const float*)d_in[6];
  const float* Wc = (const float*)d_in[7];
  const float* bc = (const float*)d_in[8];
  float* out = (float*)d_out;

  char* ws = (char*)d_ws;
  size_t off = 0;
  auto alloc = [&](size_t bytes) -> void* {
    void* p = (void*)(ws + off);
    off += (bytes + 255) & ~(size_t)255;
    return p;
  };
  int* deg = (int*)alloc((size_t)N_NODES * 4);
  int* cursor = (int*)alloc((size_t)N_NODES * 4);
  int* offs = (int*)alloc((size_t)(N_NODES + 1) * 4);
  float* dinv = (float*)alloc((size_t)N_NODES * 4);
  int* bsum = (int*)alloc((size_t)NB_SCAN * 4);
  int* bpre = (int*)alloc((size_t)NB_SCAN * 4);
  int2* csr = (int2*)alloc((size_t)N_EDGES * 8);
  ushort_t* hbuf = (ushort_t*)alloc((size_t)N_NODES * D * 2);  // conv in (bf16)
  ushort_t* x2 = (ushort_t*)alloc((size_t)N_NODES * D * 2);    // relu(conv1) bf16
  float* h2f = (float*)alloc((size_t)N_NODES * D * 4);         // conv2 out f32
  float* sums = (float*)alloc((size_t)N_GRAPHS * D * 4);
  int* cnts = (int*)alloc((size_t)N_GRAPHS * 4);

  hipMemsetAsync(deg, 0, (size_t)N_NODES * 4, stream);
  hipMemsetAsync(sums, 0, (size_t)N_GRAPHS * D * 4, stream);
  hipMemsetAsync(cnts, 0, (size_t)N_GRAPHS * 4, stream);

  k_hist<<<(N_EDGES + 255) / 256, 256, 0, stream>>>(ei, deg);
  k_dinv<<<(N_NODES + 255) / 256, 256, 0, stream>>>(deg, dinv);
  k_bsum<<<NB_SCAN, 256, 0, stream>>>(deg, bsum);
  k_spart<<<1, 256, 0, stream>>>(bsum, bpre, offs);
  k_fill<<<NB_SCAN, 256, 0, stream>>>(deg, bpre, offs, cursor);
  k_csr<<<(N_EDGES + 255) / 256, 256, 0, stream>>>(ei, dinv, cursor, csr);

  k_gemm<float><<<(N_NODES + 63) / 64, 256, 0, stream>>>(x, W1, hbuf);
  k_agg<0><<<(N_NODES + 3) / 4, 256, 0, stream>>>(hbuf, csr, offs, dinv, b1, x2, nullptr);
  k_gemm<ushort_t><<<(N_NODES + 63) / 64, 256, 0, stream>>>(x2, W2, hbuf);
  k_agg<1><<<(N_NODES + 3) / 4, 256, 0, stream>>>(hbuf, csr, offs, dinv, b2, nullptr, h2f);

  k_cnt<<<(N_NODES + 255) / 256, 256, 0, stream>>>(batch, cnts);
  k_pool<<<(N_NODES + 255) / 256, 128, 0, stream>>>(h2f, batch, sums);
  k_final<<<N_GRAPHS, 128, 0, stream>>>(sums, cnts, Wc, bc, out);
}

// Round 3
// 404.214 us; speedup vs baseline: 1.5560x; 1.1818x over previous
//
#include <hip/hip_runtime.h>

#define N_NODES 50000
#define N_EDGES 800000
#define D 128
#define N_GRAPHS 256
#define N_CLASSES 16
#define NB_SCAN ((N_NODES + 255) / 256)  // 196

typedef unsigned short ushort_t;
typedef unsigned int uint_t;

__device__ __forceinline__ float bf2f(uint_t u) {
  return __uint_as_float(u << 16);
}
__device__ __forceinline__ uint_t f2bf(float f) {
  uint_t x = __float_as_uint(f);
  return (x + 0x7fffu + ((x >> 16) & 1u)) >> 16;
}

// ---- edge histogram (in-degree over dst) + per-graph node counts ----
__global__ void k_pre(const int* __restrict__ ei, const int* __restrict__ batch,
                      int* __restrict__ deg, int* __restrict__ cnts) {
  int e = blockIdx.x * blockDim.x + threadIdx.x;
  if (e < N_EDGES) atomicAdd(&deg[ei[N_EDGES + e]], 1);
  if (e < N_NODES) atomicAdd(&cnts[batch[e]], 1);
}

// ---- block sums of deg (for scan) + dinv = rsqrt(deg+1) fused ----
__global__ __launch_bounds__(256) void k_bsum(const int* __restrict__ deg,
                                              float* __restrict__ dinv,
                                              int* __restrict__ bsum) {
  int t = threadIdx.x;
  int i = blockIdx.x * 256 + t;
  int d = 0;
  if (i < N_NODES) {
    d = deg[i];
    dinv[i] = rsqrtf((float)(d + 1));
  }
#pragma unroll
  for (int o = 1; o < 64; o <<= 1) d += __shfl_xor(d, o);
  __shared__ int ws[4];
  if ((t & 63) == 0) ws[t >> 6] = d;
  __syncthreads();
  if (t == 0) bsum[blockIdx.x] = ws[0] + ws[1] + ws[2] + ws[3];
}

// ---- scan the 196 partials (1 block) ----
__global__ __launch_bounds__(256) void k_spart(const int* __restrict__ bsum,
                                               int* __restrict__ bpre,
                                               int* __restrict__ offs) {
  int t = threadIdx.x;
  int lane = t & 63, wid = t >> 6;
  int d = (t < NB_SCAN) ? bsum[t] : 0;
  int v = d;
#pragma unroll
  for (int o = 1; o < 64; o <<= 1) {
    int u = __shfl_up(v, o);
    if (lane >= o) v += u;
  }
  __shared__ int ws[4];
  if (lane == 63) ws[wid] = v;
  __syncthreads();
  int add = 0;
  for (int w = 0; w < wid; ++w) add += ws[w];
  int excl = v - d + add;
  if (t < NB_SCAN) bpre[t] = excl;
  if (t == NB_SCAN - 1) offs[N_NODES] = excl + d;
}

// ---- fill offsets/cursor with in-block wave scan ----
__global__ __launch_bounds__(256) void k_fill(const int* __restrict__ deg,
                                              const int* __restrict__ bpre,
                                              int* __restrict__ offs,
                                              int* __restrict__ cursor) {
  int t = threadIdx.x;
  int i = blockIdx.x * 256 + t;
  int d = (i < N_NODES) ? deg[i] : 0;
  int lane = t & 63, wid = t >> 6;
  int v = d;
#pragma unroll
  for (int o = 1; o < 64; o <<= 1) {
    int u = __shfl_up(v, o);
    if (lane >= o) v += u;
  }
  __shared__ int ws[4];
  if (lane == 63) ws[wid] = v;
  __syncthreads();
  int add = bpre[blockIdx.x];
  for (int w = 0; w < wid; ++w) add += ws[w];
  int excl = v - d + add;
  if (i < N_NODES) {
    offs[i] = excl;
    cursor[i] = excl;
  }
}

// ---- counting-sort edges by dst into CSR (src, weight) ----
__global__ void k_csr(const int* __restrict__ ei, const float* __restrict__ dinv,
                      int* __restrict__ cursor, int2* __restrict__ csr) {
  int e = blockIdx.x * blockDim.x + threadIdx.x;
  if (e >= N_EDGES) return;
  int s = ei[e];
  int d = ei[N_EDGES + e];
  int pos = atomicAdd(&cursor[d], 1);
  float w = dinv[s] * dinv[d];
  csr[pos] = make_int2(s, __float_as_int(w));
}

// ---- GEMM: [N x 128] @ [128 x 128] -> bf16 out. W staged in LDS. ----
template <typename TIN>
__global__ __launch_bounds__(256) void k_gemm(const TIN* __restrict__ A,
                                              const float* __restrict__ W,
                                              ushort_t* __restrict__ Out) {
  __shared__ float Asm[64][128];   // 32 KB
  __shared__ float Wsm[128][128];  // 64 KB
  int t = threadIdx.x;
  const float4* W4 = (const float4*)W;
  float4* Ws4 = (float4*)&Wsm[0][0];
#pragma unroll
  for (int i = 0; i < 16; ++i) Ws4[t + 256 * i] = W4[t + 256 * i];
  int row0 = blockIdx.x * 64;
  if constexpr (sizeof(TIN) == 4) {  // fp32 input
    const float4* A4 = (const float4*)(A + (size_t)row0 * D);
    float4* As4 = (float4*)&Asm[0][0];
#pragma unroll
    for (int i = 0; i < 8; ++i) {
      int idx = t + 256 * i;  // float4 index, 32 per row
      int r = idx >> 5;
      float4 v = make_float4(0.f, 0.f, 0.f, 0.f);
      if (row0 + r < N_NODES) v = A4[idx];
      As4[idx] = v;
    }
  } else {  // bf16 input
    const uint4* A8 = (const uint4*)(A + (size_t)row0 * D);
#pragma unroll
    for (int i = 0; i < 4; ++i) {
      int idx = t + 256 * i;  // uint4 (8 bf16) index, 16 per row
      int r = idx >> 4;
      uint4 v = make_uint4(0, 0, 0, 0);
      if (row0 + r < N_NODES) v = A8[idx];
      float* dst = &Asm[0][0] + (size_t)idx * 8;
      dst[0] = bf2f(v.x & 0xffffu); dst[1] = bf2f(v.x >> 16);
      dst[2] = bf2f(v.y & 0xffffu); dst[3] = bf2f(v.y >> 16);
      dst[4] = bf2f(v.z & 0xffffu); dst[5] = bf2f(v.z >> 16);
      dst[6] = bf2f(v.w & 0xffffu); dst[7] = bf2f(v.w >> 16);
    }
  }
  __syncthreads();
  int tr = t >> 5, tc = t & 31;  // 8 row-groups x 32 col-threads
  float acc[8][4] = {};
  for (int k = 0; k < D; ++k) {
    float4 w = *(const float4*)&Wsm[k][tc * 4];
#pragma unroll
    for (int i = 0; i < 8; ++i) {
      float a = Asm[tr * 8 + i][k];
      acc[i][0] = fmaf(a, w.x, acc[i][0]);
      acc[i][1] = fmaf(a, w.y, acc[i][1]);
      acc[i][2] = fmaf(a, w.z, acc[i][2]);
      acc[i][3] = fmaf(a, w.w, acc[i][3]);
    }
  }
#pragma unroll
  for (int i = 0; i < 8; ++i) {
    int r = row0 + tr * 8 + i;
    if (r < N_NODES) {
      uint_t lo = f2bf(acc[i][0]) | (f2bf(acc[i][1]) << 16);
      uint_t hi = f2bf(acc[i][2]) | (f2bf(acc[i][3]) << 16);
      *(uint2*)(Out + (size_t)r * D + tc * 4) = make_uint2(lo, hi);
    }
  }
}

// ---- agg layer1: one wave per node; relu(agg + b1) -> bf16 ----
__global__ __launch_bounds__(256) void k_agg_relu(const ushort_t* __restrict__ h,
                                                  const int2* __restrict__ csr,
                                                  const int* __restrict__ offs,
                                                  const float* __restrict__ dinv,
                                                  const float* __restrict__ bias,
                                                  ushort_t* __restrict__ obf) {
  int wv = threadIdx.x >> 6;
  int lane = threadIdx.x & 63;
  int node = blockIdx.x * 4 + wv;
  int grp = lane >> 4;   // 0..3: which edge of the chunk
  int gl = lane & 15;    // lane in group
  int d0 = gl * 8;       // dims [d0, d0+8)
  int beg = offs[node], end = offs[node + 1];
  float acc[8] = {0.f, 0.f, 0.f, 0.f, 0.f, 0.f, 0.f, 0.f};
  for (int base = beg + grp; base < end; base += 4) {
    int2 e = csr[base];  // all 16 lanes in group: same addr (broadcast)
    float w = __int_as_float(e.y);
    uint4 v = *(const uint4*)(h + (size_t)e.x * D + d0);
    acc[0] = fmaf(w, bf2f(v.x & 0xffffu), acc[0]);
    acc[1] = fmaf(w, bf2f(v.x >> 16), acc[1]);
    acc[2] = fmaf(w, bf2f(v.y & 0xffffu), acc[2]);
    acc[3] = fmaf(w, bf2f(v.y >> 16), acc[3]);
    acc[4] = fmaf(w, bf2f(v.z & 0xffffu), acc[4]);
    acc[5] = fmaf(w, bf2f(v.z >> 16), acc[5]);
    acc[6] = fmaf(w, bf2f(v.w & 0xffffu), acc[6]);
    acc[7] = fmaf(w, bf2f(v.w >> 16), acc[7]);
  }
#pragma unroll
  for (int m = 16; m <= 32; m <<= 1) {
#pragma unroll
    for (int i = 0; i < 8; ++i) acc[i] += __shfl_xor(acc[i], m);
  }
  if (grp == 0) {
    float dn = dinv[node];
    float wsl = dn * dn;
    uint4 v = *(const uint4*)(h + (size_t)node * D + d0);
    acc[0] = fmaf(wsl, bf2f(v.x & 0xffffu), acc[0]);
    acc[1] = fmaf(wsl, bf2f(v.x >> 16), acc[1]);
    acc[2] = fmaf(wsl, bf2f(v.y & 0xffffu), acc[2]);
    acc[3] = fmaf(wsl, bf2f(v.y >> 16), acc[3]);
    acc[4] = fmaf(wsl, bf2f(v.z & 0xffffu), acc[4]);
    acc[5] = fmaf(wsl, bf2f(v.z >> 16), acc[5]);
    acc[6] = fmaf(wsl, bf2f(v.w & 0xffffu), acc[6]);
    acc[7] = fmaf(wsl, bf2f(v.w >> 16), acc[7]);
    float4 blo = *(const float4*)(bias + d0);
    float4 bhi = *(const float4*)(bias + d0 + 4);
    acc[0] += blo.x; acc[1] += blo.y; acc[2] += blo.z; acc[3] += blo.w;
    acc[4] += bhi.x; acc[5] += bhi.y; acc[6] += bhi.z; acc[7] += bhi.w;
#pragma unroll
    for (int i = 0; i < 8; ++i) acc[i] = fmaxf(acc[i], 0.f);
    uint4 o;
    o.x = f2bf(acc[0]) | (f2bf(acc[1]) << 16);
    o.y = f2bf(acc[2]) | (f2bf(acc[3]) << 16);
    o.z = f2bf(acc[4]) | (f2bf(acc[5]) << 16);
    o.w = f2bf(acc[6]) | (f2bf(acc[7]) << 16);
    *(uint4*)(obf + (size_t)node * D + d0) = o;
  }
}

// ---- agg layer2 fused with mean-pool: sums[g] += agg(node)/cnt[g] ----
// 4 waves/block, each wave handles 4 consecutive nodes (block = 16 nodes).
// Bias b2 is NOT applied here (moved to k_final: mean(agg+b2)=mean(agg)+b2).
__global__ __launch_bounds__(256) void k_agg_pool(const ushort_t* __restrict__ h,
                                                   const int2* __restrict__ csr,
                                                   const int* __restrict__ offs,
                                                   const float* __restrict__ dinv,
                                                   const int* __restrict__ batch,
                                                   const int* __restrict__ cnts,
                                                   float* __restrict__ sums) {
  __shared__ float pool[128];
  int t = threadIdx.x;
  int wv = t >> 6, lane = t & 63;
  int grp = lane >> 4, gl = lane & 15;
  int d0 = gl * 8;
  int node0 = blockIdx.x * 16;  // N_NODES % 16 == 0
  int g0 = batch[node0];
  if (t < 128) pool[t] = 0.f;
  __syncthreads();
  float pacc[8] = {0.f, 0.f, 0.f, 0.f, 0.f, 0.f, 0.f, 0.f};
  for (int i = 0; i < 4; ++i) {
    int node = node0 + wv * 4 + i;
    int beg = offs[node], end = offs[node + 1];
    float acc[8] = {0.f, 0.f, 0.f, 0.f, 0.f, 0.f, 0.f, 0.f};
    for (int base = beg + grp; base < end; base += 4) {
      int2 e = csr[base];
      float w = __int_as_float(e.y);
      uint4 v = *(const uint4*)(h + (size_t)e.x * D + d0);
      acc[0] = fmaf(w, bf2f(v.x & 0xffffu), acc[0]);
      acc[1] = fmaf(w, bf2f(v.x >> 16), acc[1]);
      acc[2] = fmaf(w, bf2f(v.y & 0xffffu), acc[2]);
      acc[3] = fmaf(w, bf2f(v.y >> 16), acc[3]);
      acc[4] = fmaf(w, bf2f(v.z & 0xffffu), acc[4]);
      acc[5] = fmaf(w, bf2f(v.z >> 16), acc[5]);
      acc[6] = fmaf(w, bf2f(v.w & 0xffffu), acc[6]);
      acc[7] = fmaf(w, bf2f(v.w >> 16), acc[7]);
    }
#pragma unroll
    for (int m = 16; m <= 32; m <<= 1) {
#pragma unroll
      for (int k = 0; k < 8; ++k) acc[k] += __shfl_xor(acc[k], m);
    }
    if (grp == 0) {
      float dn = dinv[node];
      float wsl = dn * dn;
      uint4 v = *(const uint4*)(h + (size_t)node * D + d0);
      acc[0] = fmaf(wsl, bf2f(v.x & 0xffffu), acc[0]);
      acc[1] = fmaf(wsl, bf2f(v.x >> 16), acc[1]);
      acc[2] = fmaf(wsl, bf2f(v.y & 0xffffu), acc[2]);
      acc[3] = fmaf(wsl, bf2f(v.y >> 16), acc[3]);
      acc[4] = fmaf(wsl, bf2f(v.z & 0xffffu), acc[4]);
      acc[5] = fmaf(wsl, bf2f(v.z >> 16), acc[5]);
      acc[6] = fmaf(wsl, bf2f(v.w & 0xffffu), acc[6]);
      acc[7] = fmaf(wsl, bf2f(v.w >> 16), acc[7]);
      int g = batch[node];
      float rc = 1.0f / (float)cnts[g];
      if (g == g0) {
#pragma unroll
        for (int k = 0; k < 8; ++k) pacc[k] = fmaf(acc[k], rc, pacc[k]);
      } else {
#pragma unroll
        for (int k = 0; k < 8; ++k)
          atomicAdd(&sums[(size_t)g * D + d0 + k], acc[k] * rc);
      }
    }
  }
  if (grp == 0) {
#pragma unroll
    for (int k = 0; k < 8; ++k) atomicAdd(&pool[d0 + k], pacc[k]);
  }
  __syncthreads();
  if (t < 128) atomicAdd(&sums[(size_t)g0 * D + t], pool[t]);
}

// ---- mean(+b2) + final linear head ----
__global__ __launch_bounds__(128) void k_final(const float* __restrict__ sums,
                                               const float* __restrict__ b2,
                                               const float* __restrict__ Wc,
                                               const float* __restrict__ bc,
                                               float* __restrict__ out) {
  __shared__ float p[128];
  int g = blockIdx.x;
  int t = threadIdx.x;
  p[t] = sums[g * D + t] + b2[t];
  __syncthreads();
  if (t < N_CLASSES) {
    float acc = bc[t];
    for (int k = 0; k < D; ++k) acc = fmaf(p[k], Wc[k * N_CLASSES + t], acc);
    out[g * N_CLASSES + t] = acc;
  }
}

extern "C" void kernel_launch(void* const* d_in, const int* in_sizes, int n_in,
                              void* d_out, int out_size, void* d_ws, size_t ws_size,
                              hipStream_t stream) {
  const float* x = (const float*)d_in[0];
  const int* ei = (const int*)d_in[1];
  const int* batch = (const int*)d_in[2];
  const float* W1 = (const float*)d_in[3];
  const float* b1 = (const float*)d_in[4];
  const float* W2 = (const float*)d_in[5];
  const float* b2 = (const float*)d_in[6];
  const float* Wc = (const float*)d_in[7];
  const float* bc = (const float*)d_in[8];
  float* out = (float*)d_out;

  char* ws = (char*)d_ws;
  size_t off = 0;
  auto alloc = [&](size_t bytes) -> void* {
    void* p = (void*)(ws + off);
    off += (bytes + 255) & ~(size_t)255;
    return p;
  };
  // zero-init region: deg, cnts, sums contiguous at the front
  int* deg = (int*)alloc((size_t)N_NODES * 4);
  int* cnts = (int*)alloc((size_t)N_GRAPHS * 4);
  float* sums = (float*)alloc((size_t)N_GRAPHS * D * 4);
  size_t zero_bytes = off;
  int* cursor = (int*)alloc((size_t)N_NODES * 4);
  int* offs = (int*)alloc((size_t)(N_NODES + 1) * 4);
  float* dinv = (float*)alloc((size_t)N_NODES * 4);
  int* bsum = (int*)alloc((size_t)NB_SCAN * 4);
  int* bpre = (int*)alloc((size_t)NB_SCAN * 4);
  int2* csr = (int2*)alloc((size_t)N_EDGES * 8);
  ushort_t* hbuf = (ushort_t*)alloc((size_t)N_NODES * D * 2);  // conv in (bf16)
  ushort_t* x2 = (ushort_t*)alloc((size_t)N_NODES * D * 2);    // relu(conv1) bf16

  hipMemsetAsync(ws, 0, zero_bytes, stream);

  k_pre<<<(N_EDGES + 255) / 256, 256, 0, stream>>>(ei, batch, deg, cnts);
  k_bsum<<<NB_SCAN, 256, 0, stream>>>(deg, dinv, bsum);
  k_spart<<<1, 256, 0, stream>>>(bsum, bpre, offs);
  k_fill<<<NB_SCAN, 256, 0, stream>>>(deg, bpre, offs, cursor);
  k_csr<<<(N_EDGES + 255) / 256, 256, 0, stream>>>(ei, dinv, cursor, csr);

  k_gemm<float><<<(N_NODES + 63) / 64, 256, 0, stream>>>(x, W1, hbuf);
  k_agg_relu<<<N_NODES / 4, 256, 0, stream>>>(hbuf, csr, offs, dinv, b1, x2);
  k_gemm<ushort_t><<<(N_NODES + 63) / 64, 256, 0, stream>>>(x2, W2, hbuf);
  k_agg_pool<<<N_NODES / 16, 256, 0, stream>>>(hbuf, csr, offs, dinv, batch, cnts, sums);

  k_final<<<N_GRAPHS, 128, 0, stream>>>(sums, b2, Wc, bc, out);
}

// Round 4
// 326.041 us; speedup vs baseline: 1.9291x; 1.2398x over previous
//
#include <hip/hip_runtime.h>

#define N_NODES 50000
#define N_EDGES 800000
#define D 128
#define N_GRAPHS 256
#define N_CLASSES 16
#define NB_SCAN ((N_NODES + 255) / 256)  // 196

typedef unsigned short ushort_t;
typedef unsigned int uint_t;
typedef unsigned char uchar_t;

__device__ __forceinline__ float bf2f(uint_t u) {
  return __uint_as_float(u << 16);
}
__device__ __forceinline__ uint_t f2bf(float f) {
  uint_t x = __float_as_uint(f);
  return (x + 0x7fffu + ((x >> 16) & 1u)) >> 16;
}

// ---- edge histogram over dst; store each edge's rank within its bucket ----
__global__ void k_pre(const int* __restrict__ ei, int* __restrict__ deg,
                      uchar_t* __restrict__ rank) {
  int e = blockIdx.x * blockDim.x + threadIdx.x;
  if (e < N_EDGES) {
    int d = ei[N_EDGES + e];
    int r = atomicAdd(&deg[d], 1);
    rank[e] = (uchar_t)r;
  }
}

// ---- block sums of deg (for scan) + dinv = rsqrt(deg+1) fused ----
__global__ __launch_bounds__(256) void k_bsum(const int* __restrict__ deg,
                                              float* __restrict__ dinv,
                                              int* __restrict__ bsum) {
  int t = threadIdx.x;
  int i = blockIdx.x * 256 + t;
  int d = 0;
  if (i < N_NODES) {
    d = deg[i];
    dinv[i] = rsqrtf((float)(d + 1));
  }
#pragma unroll
  for (int o = 1; o < 64; o <<= 1) d += __shfl_xor(d, o);
  __shared__ int ws[4];
  if ((t & 63) == 0) ws[t >> 6] = d;
  __syncthreads();
  if (t == 0) bsum[blockIdx.x] = ws[0] + ws[1] + ws[2] + ws[3];
}

// ---- scan the 196 partials (1 block) + per-graph 1/cnt via binary search ----
__global__ __launch_bounds__(256) void k_spart(const int* __restrict__ bsum,
                                               const int* __restrict__ batch,
                                               int* __restrict__ bpre,
                                               int* __restrict__ offs,
                                               float* __restrict__ rcnts) {
  int t = threadIdx.x;
  int lane = t & 63, wid = t >> 6;
  int d = (t < NB_SCAN) ? bsum[t] : 0;
  int v = d;
#pragma unroll
  for (int o = 1; o < 64; o <<= 1) {
    int u = __shfl_up(v, o);
    if (lane >= o) v += u;
  }
  __shared__ int ws[4];
  __shared__ int bound[256];
  if (lane == 63) ws[wid] = v;
  // batch is sorted: bound[g] = first index with batch[idx] >= g
  {
    int g = t;
    int lo = 0, hi = N_NODES;
    while (lo < hi) {
      int m = (lo + hi) >> 1;
      if (batch[m] < g) lo = m + 1; else hi = m;
    }
    bound[g] = lo;
  }
  __syncthreads();
  int add = 0;
  for (int w = 0; w < wid; ++w) add += ws[w];
  int excl = v - d + add;
  if (t < NB_SCAN) bpre[t] = excl;
  if (t == NB_SCAN - 1) offs[N_NODES] = excl + d;
  int cnt = ((t == 255) ? N_NODES : bound[t + 1]) - bound[t];
  rcnts[t] = 1.0f / (float)max(cnt, 1);
}

// ---- fill offsets with in-block wave scan ----
__global__ __launch_bounds__(256) void k_fill(const int* __restrict__ deg,
                                              const int* __restrict__ bpre,
                                              int* __restrict__ offs) {
  int t = threadIdx.x;
  int i = blockIdx.x * 256 + t;
  int d = (i < N_NODES) ? deg[i] : 0;
  int lane = t & 63, wid = t >> 6;
  int v = d;
#pragma unroll
  for (int o = 1; o < 64; o <<= 1) {
    int u = __shfl_up(v, o);
    if (lane >= o) v += u;
  }
  __shared__ int ws[4];
  if (lane == 63) ws[wid] = v;
  __syncthreads();
  int add = bpre[blockIdx.x];
  for (int w = 0; w < wid; ++w) add += ws[w];
  int excl = v - d + add;
  if (i < N_NODES) offs[i] = excl;
}

// ---- CSR fill, atomic-free: pos = offs[dst] + rank[e] ----
__global__ void k_csr(const int* __restrict__ ei, const float* __restrict__ dinv,
                      const int* __restrict__ offs, const uchar_t* __restrict__ rank,
                      int2* __restrict__ csr) {
  int e = blockIdx.x * blockDim.x + threadIdx.x;
  if (e >= N_EDGES) return;
  int s = ei[e];
  int d = ei[N_EDGES + e];
  int pos = offs[d] + (int)rank[e];
  float w = dinv[s] * dinv[d];
  csr[pos] = make_int2(s, __float_as_int(w));
}

// ---- GEMM: [N x 128] @ [128 x 128] -> bf16 out. W staged in LDS. ----
template <typename TIN>
__global__ __launch_bounds__(256) void k_gemm(const TIN* __restrict__ A,
                                              const float* __restrict__ W,
                                              ushort_t* __restrict__ Out) {
  __shared__ float Asm[64][128];   // 32 KB
  __shared__ float Wsm[128][128];  // 64 KB
  int t = threadIdx.x;
  const float4* W4 = (const float4*)W;
  float4* Ws4 = (float4*)&Wsm[0][0];
#pragma unroll
  for (int i = 0; i < 16; ++i) Ws4[t + 256 * i] = W4[t + 256 * i];
  int row0 = blockIdx.x * 64;
  if constexpr (sizeof(TIN) == 4) {  // fp32 input
    const float4* A4 = (const float4*)(A + (size_t)row0 * D);
    float4* As4 = (float4*)&Asm[0][0];
#pragma unroll
    for (int i = 0; i < 8; ++i) {
      int idx = t + 256 * i;  // float4 index, 32 per row
      int r = idx >> 5;
      float4 v = make_float4(0.f, 0.f, 0.f, 0.f);
      if (row0 + r < N_NODES) v = A4[idx];
      As4[idx] = v;
    }
  } else {  // bf16 input
    const uint4* A8 = (const uint4*)(A + (size_t)row0 * D);
#pragma unroll
    for (int i = 0; i < 4; ++i) {
      int idx = t + 256 * i;  // uint4 (8 bf16) index, 16 per row
      int r = idx >> 4;
      uint4 v = make_uint4(0, 0, 0, 0);
      if (row0 + r < N_NODES) v = A8[idx];
      float* dst = &Asm[0][0] + (size_t)idx * 8;
      dst[0] = bf2f(v.x & 0xffffu); dst[1] = bf2f(v.x >> 16);
      dst[2] = bf2f(v.y & 0xffffu); dst[3] = bf2f(v.y >> 16);
      dst[4] = bf2f(v.z & 0xffffu); dst[5] = bf2f(v.z >> 16);
      dst[6] = bf2f(v.w & 0xffffu); dst[7] = bf2f(v.w >> 16);
    }
  }
  __syncthreads();
  int tr = t >> 5, tc = t & 31;  // 8 row-groups x 32 col-threads
  float acc[8][4] = {};
  for (int k = 0; k < D; ++k) {
    float4 w = *(const float4*)&Wsm[k][tc * 4];
#pragma unroll
    for (int i = 0; i < 8; ++i) {
      float a = Asm[tr * 8 + i][k];
      acc[i][0] = fmaf(a, w.x, acc[i][0]);
      acc[i][1] = fmaf(a, w.y, acc[i][1]);
      acc[i][2] = fmaf(a, w.z, acc[i][2]);
      acc[i][3] = fmaf(a, w.w, acc[i][3]);
    }
  }
#pragma unroll
  for (int i = 0; i < 8; ++i) {
    int r = row0 + tr * 8 + i;
    if (r < N_NODES) {
      uint_t lo = f2bf(acc[i][0]) | (f2bf(acc[i][1]) << 16);
      uint_t hi = f2bf(acc[i][2]) | (f2bf(acc[i][3]) << 16);
      *(uint2*)(Out + (size_t)r * D + tc * 4) = make_uint2(lo, hi);
    }
  }
}

// ---- agg layer1: one wave per node; relu(agg + b1) -> bf16 ----
__global__ __launch_bounds__(256) void k_agg_relu(const ushort_t* __restrict__ h,
                                                  const int2* __restrict__ csr,
                                                  const int* __restrict__ offs,
                                                  const float* __restrict__ dinv,
                                                  const float* __restrict__ bias,
                                                  ushort_t* __restrict__ obf) {
  int wv = threadIdx.x >> 6;
  int lane = threadIdx.x & 63;
  int node = blockIdx.x * 4 + wv;
  int grp = lane >> 4;   // 0..3: which edge of the chunk
  int gl = lane & 15;    // lane in group
  int d0 = gl * 8;       // dims [d0, d0+8)
  int beg = offs[node], end = offs[node + 1];
  float acc[8] = {0.f, 0.f, 0.f, 0.f, 0.f, 0.f, 0.f, 0.f};
  for (int base = beg + grp; base < end; base += 4) {
    int2 e = csr[base];  // all 16 lanes in group: same addr (broadcast)
    float w = __int_as_float(e.y);
    uint4 v = *(const uint4*)(h + (size_t)e.x * D + d0);
    acc[0] = fmaf(w, bf2f(v.x & 0xffffu), acc[0]);
    acc[1] = fmaf(w, bf2f(v.x >> 16), acc[1]);
    acc[2] = fmaf(w, bf2f(v.y & 0xffffu), acc[2]);
    acc[3] = fmaf(w, bf2f(v.y >> 16), acc[3]);
    acc[4] = fmaf(w, bf2f(v.z & 0xffffu), acc[4]);
    acc[5] = fmaf(w, bf2f(v.z >> 16), acc[5]);
    acc[6] = fmaf(w, bf2f(v.w & 0xffffu), acc[6]);
    acc[7] = fmaf(w, bf2f(v.w >> 16), acc[7]);
  }
#pragma unroll
  for (int m = 16; m <= 32; m <<= 1) {
#pragma unroll
    for (int i = 0; i < 8; ++i) acc[i] += __shfl_xor(acc[i], m);
  }
  if (grp == 0) {
    float dn = dinv[node];
    float wsl = dn * dn;
    uint4 v = *(const uint4*)(h + (size_t)node * D + d0);
    acc[0] = fmaf(wsl, bf2f(v.x & 0xffffu), acc[0]);
    acc[1] = fmaf(wsl, bf2f(v.x >> 16), acc[1]);
    acc[2] = fmaf(wsl, bf2f(v.y & 0xffffu), acc[2]);
    acc[3] = fmaf(wsl, bf2f(v.y >> 16), acc[3]);
    acc[4] = fmaf(wsl, bf2f(v.z & 0xffffu), acc[4]);
    acc[5] = fmaf(wsl, bf2f(v.z >> 16), acc[5]);
    acc[6] = fmaf(wsl, bf2f(v.w & 0xffffu), acc[6]);
    acc[7] = fmaf(wsl, bf2f(v.w >> 16), acc[7]);
    float4 blo = *(const float4*)(bias + d0);
    float4 bhi = *(const float4*)(bias + d0 + 4);
    acc[0] += blo.x; acc[1] += blo.y; acc[2] += blo.z; acc[3] += blo.w;
    acc[4] += bhi.x; acc[5] += bhi.y; acc[6] += bhi.z; acc[7] += bhi.w;
#pragma unroll
    for (int i = 0; i < 8; ++i) acc[i] = fmaxf(acc[i], 0.f);
    uint4 o;
    o.x = f2bf(acc[0]) | (f2bf(acc[1]) << 16);
    o.y = f2bf(acc[2]) | (f2bf(acc[3]) << 16);
    o.z = f2bf(acc[4]) | (f2bf(acc[5]) << 16);
    o.w = f2bf(acc[6]) | (f2bf(acc[7]) << 16);
    *(uint4*)(obf + (size_t)node * D + d0) = o;
  }
}

// ---- agg layer2 fused with mean-pool: sums[g] += agg(node)/cnt[g] ----
__global__ __launch_bounds__(256) void k_agg_pool(const ushort_t* __restrict__ h,
                                                   const int2* __restrict__ csr,
                                                   const int* __restrict__ offs,
                                                   const float* __restrict__ dinv,
                                                   const int* __restrict__ batch,
                                                   const float* __restrict__ rcnts,
                                                   float* __restrict__ sums) {
  __shared__ float pool[128];
  int t = threadIdx.x;
  int wv = t >> 6, lane = t & 63;
  int grp = lane >> 4, gl = lane & 15;
  int d0 = gl * 8;
  int node0 = blockIdx.x * 16;  // N_NODES % 16 == 0
  int g0 = batch[node0];
  if (t < 128) pool[t] = 0.f;
  __syncthreads();
  float pacc[8] = {0.f, 0.f, 0.f, 0.f, 0.f, 0.f, 0.f, 0.f};
  for (int i = 0; i < 4; ++i) {
    int node = node0 + wv * 4 + i;
    int beg = offs[node], end = offs[node + 1];
    float acc[8] = {0.f, 0.f, 0.f, 0.f, 0.f, 0.f, 0.f, 0.f};
    for (int base = beg + grp; base < end; base += 4) {
      int2 e = csr[base];
      float w = __int_as_float(e.y);
      uint4 v = *(const uint4*)(h + (size_t)e.x * D + d0);
      acc[0] = fmaf(w, bf2f(v.x & 0xffffu), acc[0]);
      acc[1] = fmaf(w, bf2f(v.x >> 16), acc[1]);
      acc[2] = fmaf(w, bf2f(v.y & 0xffffu), acc[2]);
      acc[3] = fmaf(w, bf2f(v.y >> 16), acc[3]);
      acc[4] = fmaf(w, bf2f(v.z & 0xffffu), acc[4]);
      acc[5] = fmaf(w, bf2f(v.z >> 16), acc[5]);
      acc[6] = fmaf(w, bf2f(v.w & 0xffffu), acc[6]);
      acc[7] = fmaf(w, bf2f(v.w >> 16), acc[7]);
    }
#pragma unroll
    for (int m = 16; m <= 32; m <<= 1) {
#pragma unroll
      for (int k = 0; k < 8; ++k) acc[k] += __shfl_xor(acc[k], m);
    }
    if (grp == 0) {
      float dn = dinv[node];
      float wsl = dn * dn;
      uint4 v = *(const uint4*)(h + (size_t)node * D + d0);
      acc[0] = fmaf(wsl, bf2f(v.x & 0xffffu), acc[0]);
      acc[1] = fmaf(wsl, bf2f(v.x >> 16), acc[1]);
      acc[2] = fmaf(wsl, bf2f(v.y & 0xffffu), acc[2]);
      acc[3] = fmaf(wsl, bf2f(v.y >> 16), acc[3]);
      acc[4] = fmaf(wsl, bf2f(v.z & 0xffffu), acc[4]);
      acc[5] = fmaf(wsl, bf2f(v.z >> 16), acc[5]);
      acc[6] = fmaf(wsl, bf2f(v.w & 0xffffu), acc[6]);
      acc[7] = fmaf(wsl, bf2f(v.w >> 16), acc[7]);
      int g = batch[node];
      float rc = rcnts[g];
      if (g == g0) {
#pragma unroll
        for (int k = 0; k < 8; ++k) pacc[k] = fmaf(acc[k], rc, pacc[k]);
      } else {
#pragma unroll
        for (int k = 0; k < 8; ++k)
          atomicAdd(&sums[(size_t)g * D + d0 + k], acc[k] * rc);
      }
    }
  }
  if (grp == 0) {
#pragma unroll
    for (int k = 0; k < 8; ++k) atomicAdd(&pool[d0 + k], pacc[k]);
  }
  __syncthreads();
  if (t < 128) atomicAdd(&sums[(size_t)g0 * D + t], pool[t]);
}

// ---- mean(+b2) + final linear head ----
__global__ __launch_bounds__(128) void k_final(const float* __restrict__ sums,
                                               const float* __restrict__ b2,
                                               const float* __restrict__ Wc,
                                               const float* __restrict__ bc,
                                               float* __restrict__ out) {
  __shared__ float p[128];
  int g = blockIdx.x;
  int t = threadIdx.x;
  p[t] = sums[g * D + t] + b2[t];
  __syncthreads();
  if (t < N_CLASSES) {
    float acc = bc[t];
    for (int k = 0; k < D; ++k) acc = fmaf(p[k], Wc[k * N_CLASSES + t], acc);
    out[g * N_CLASSES + t] = acc;
  }
}

extern "C" void kernel_launch(void* const* d_in, const int* in_sizes, int n_in,
                              void* d_out, int out_size, void* d_ws, size_t ws_size,
                              hipStream_t stream) {
  const float* x = (const float*)d_in[0];
  const int* ei = (const int*)d_in[1];
  const int* batch = (const int*)d_in[2];
  const float* W1 = (const float*)d_in[3];
  const float* b1 = (const float*)d_in[4];
  const float* W2 = (const float*)d_in[5];
  const float* b2 = (const float*)d_in[6];
  const float* Wc = (const float*)d_in[7];
  const float* bc = (const float*)d_in[8];
  float* out = (float*)d_out;

  char* ws = (char*)d_ws;
  size_t off = 0;
  auto alloc = [&](size_t bytes) -> void* {
    void* p = (void*)(ws + off);
    off += (bytes + 255) & ~(size_t)255;
    return p;
  };
  // zero-init region: deg, sums contiguous at the front
  int* deg = (int*)alloc((size_t)N_NODES * 4);
  float* sums = (float*)alloc((size_t)N_GRAPHS * D * 4);
  size_t zero_bytes = off;
  int* offs = (int*)alloc((size_t)(N_NODES + 1) * 4);
  float* dinv = (float*)alloc((size_t)N_NODES * 4);
  float* rcnts = (float*)alloc((size_t)N_GRAPHS * 4);
  int* bsum = (int*)alloc((size_t)NB_SCAN * 4);
  int* bpre = (int*)alloc((size_t)NB_SCAN * 4);
  uchar_t* rank = (uchar_t*)alloc((size_t)N_EDGES);
  int2* csr = (int2*)alloc((size_t)N_EDGES * 8);
  ushort_t* hbuf = (ushort_t*)alloc((size_t)N_NODES * D * 2);  // conv in (bf16)
  ushort_t* x2 = (ushort_t*)alloc((size_t)N_NODES * D * 2);    // relu(conv1) bf16

  hipMemsetAsync(ws, 0, zero_bytes, stream);

  k_pre<<<(N_EDGES + 255) / 256, 256, 0, stream>>>(ei, deg, rank);
  k_bsum<<<NB_SCAN, 256, 0, stream>>>(deg, dinv, bsum);
  k_spart<<<1, 256, 0, stream>>>(bsum, batch, bpre, offs, rcnts);
  k_fill<<<NB_SCAN, 256, 0, stream>>>(deg, bpre, offs);
  k_csr<<<(N_EDGES + 255) / 256, 256, 0, stream>>>(ei, dinv, offs, rank, csr);

  k_gemm<float><<<(N_NODES + 63) / 64, 256, 0, stream>>>(x, W1, hbuf);
  k_agg_relu<<<N_NODES / 4, 256, 0, stream>>>(hbuf, csr, offs, dinv, b1, x2);
  k_gemm<ushort_t><<<(N_NODES + 63) / 64, 256, 0, stream>>>(x2, W2, hbuf);
  k_agg_pool<<<N_NODES / 16, 256, 0, stream>>>(hbuf, csr, offs, dinv, batch, rcnts, sums);

  k_final<<<N_GRAPHS, 128, 0, stream>>>(sums, b2, Wc, bc, out);
}

// Round 5
// 262.594 us; speedup vs baseline: 2.3952x; 1.2416x over previous
//
#include <hip/hip_runtime.h>

#define N_NODES 50000
#define N_EDGES 800000
#define D 128
#define N_GRAPHS 256
#define N_CLASSES 16
#define NB_SCAN ((N_NODES + 255) / 256)  // 196

typedef unsigned short ushort_t;
typedef unsigned int uint_t;
typedef unsigned char uchar_t;
typedef __attribute__((ext_vector_type(8))) short bf16x8;
typedef __attribute__((ext_vector_type(4))) float f32x4;

__device__ __forceinline__ float bf2f(uint_t u) {
  return __uint_as_float(u << 16);
}
__device__ __forceinline__ uint_t f2bf(float f) {
  uint_t x = __float_as_uint(f);
  return (x + 0x7fffu + ((x >> 16) & 1u)) >> 16;
}

// ---- edge histogram over dst; store each edge's rank within its bucket ----
__global__ void k_pre(const int* __restrict__ ei, int* __restrict__ deg,
                      uchar_t* __restrict__ rank) {
  int e = blockIdx.x * blockDim.x + threadIdx.x;
  if (e < N_EDGES) {
    int d = ei[N_EDGES + e];
    int r = atomicAdd(&deg[d], 1);
    rank[e] = (uchar_t)r;
  }
}

// ---- pack W (fp32 [128][128], k-major rows) into MFMA B-fragment order ----
// Wf[(n*4+s)*64 + lane] = 8 bf16: B[k = s*32+(lane>>4)*8+j][col = n*16+(lane&15)]
__global__ __launch_bounds__(256) void k_wprep(const float* __restrict__ W1,
                                               const float* __restrict__ W2,
                                               uint4* __restrict__ W1f,
                                               uint4* __restrict__ W2f) {
  int slot = blockIdx.x * 256 + threadIdx.x;  // 0..4095
  const float* W = (slot < 2048) ? W1 : W2;
  uint4* Wf = (slot < 2048) ? W1f : W2f;
  int sl = slot & 2047;
  int lane = sl & 63;
  int s = (sl >> 6) & 3;
  int n = sl >> 8;
  int col = n * 16 + (lane & 15);
  int k0 = s * 32 + (lane >> 4) * 8;
  uint4 o;
  o.x = f2bf(W[(size_t)(k0 + 0) * D + col]) | (f2bf(W[(size_t)(k0 + 1) * D + col]) << 16);
  o.y = f2bf(W[(size_t)(k0 + 2) * D + col]) | (f2bf(W[(size_t)(k0 + 3) * D + col]) << 16);
  o.z = f2bf(W[(size_t)(k0 + 4) * D + col]) | (f2bf(W[(size_t)(k0 + 5) * D + col]) << 16);
  o.w = f2bf(W[(size_t)(k0 + 6) * D + col]) | (f2bf(W[(size_t)(k0 + 7) * D + col]) << 16);
  Wf[sl] = o;
}

// ---- block sums of deg (for scan) + dinv = rsqrt(deg+1) fused ----
__global__ __launch_bounds__(256) void k_bsum(const int* __restrict__ deg,
                                              float* __restrict__ dinv,
                                              int* __restrict__ bsum) {
  int t = threadIdx.x;
  int i = blockIdx.x * 256 + t;
  int d = 0;
  if (i < N_NODES) {
    d = deg[i];
    dinv[i] = rsqrtf((float)(d + 1));
  }
#pragma unroll
  for (int o = 1; o < 64; o <<= 1) d += __shfl_xor(d, o);
  __shared__ int ws[4];
  if ((t & 63) == 0) ws[t >> 6] = d;
  __syncthreads();
  if (t == 0) bsum[blockIdx.x] = ws[0] + ws[1] + ws[2] + ws[3];
}

// ---- scan the 196 partials (1 block) + per-graph 1/cnt via binary search ----
__global__ __launch_bounds__(256) void k_spart(const int* __restrict__ bsum,
                                               const int* __restrict__ batch,
                                               int* __restrict__ bpre,
                                               int* __restrict__ offs,
                                               float* __restrict__ rcnts) {
  int t = threadIdx.x;
  int lane = t & 63, wid = t >> 6;
  int d = (t < NB_SCAN) ? bsum[t] : 0;
  int v = d;
#pragma unroll
  for (int o = 1; o < 64; o <<= 1) {
    int u = __shfl_up(v, o);
    if (lane >= o) v += u;
  }
  __shared__ int ws[4];
  __shared__ int bound[256];
  if (lane == 63) ws[wid] = v;
  // batch is sorted: bound[g] = first index with batch[idx] >= g
  {
    int g = t;
    int lo = 0, hi = N_NODES;
    while (lo < hi) {
      int m = (lo + hi) >> 1;
      if (batch[m] < g) lo = m + 1; else hi = m;
    }
    bound[g] = lo;
  }
  __syncthreads();
  int add = 0;
  for (int w = 0; w < wid; ++w) add += ws[w];
  int excl = v - d + add;
  if (t < NB_SCAN) bpre[t] = excl;
  if (t == NB_SCAN - 1) offs[N_NODES] = excl + d;
  int cnt = ((t == 255) ? N_NODES : bound[t + 1]) - bound[t];
  rcnts[t] = 1.0f / (float)max(cnt, 1);
}

// ---- fill offsets with in-block wave scan ----
__global__ __launch_bounds__(256) void k_fill(const int* __restrict__ deg,
                                              const int* __restrict__ bpre,
                                              int* __restrict__ offs) {
  int t = threadIdx.x;
  int i = blockIdx.x * 256 + t;
  int d = (i < N_NODES) ? deg[i] : 0;
  int lane = t & 63, wid = t >> 6;
  int v = d;
#pragma unroll
  for (int o = 1; o < 64; o <<= 1) {
    int u = __shfl_up(v, o);
    if (lane >= o) v += u;
  }
  __shared__ int ws[4];
  if (lane == 63) ws[wid] = v;
  __syncthreads();
  int add = bpre[blockIdx.x];
  for (int w = 0; w < wid; ++w) add += ws[w];
  int excl = v - d + add;
  if (i < N_NODES) offs[i] = excl;
}

// ---- CSR fill, atomic-free: pos = offs[dst] + rank[e] ----
__global__ void k_csr(const int* __restrict__ ei, const float* __restrict__ dinv,
                      const int* __restrict__ offs, const uchar_t* __restrict__ rank,
                      int2* __restrict__ csr) {
  int e = blockIdx.x * blockDim.x + threadIdx.x;
  if (e >= N_EDGES) return;
  int s = ei[e];
  int d = ei[N_EDGES + e];
  int pos = offs[d] + (int)rank[e];
  float w = dinv[s] * dinv[d];
  csr[pos] = make_int2(s, __float_as_int(w));
}

// ---- MFMA GEMM: [N x 128] @ [128 x 128] -> bf16. No LDS.
// wave = 16 rows x 128 cols; block = 4 waves = 64 rows.
// A frag: lane holds A[row=lane&15][k=(lane>>4)*8+j]; B pre-packed by k_wprep.
template <typename TIN>
__global__ __launch_bounds__(256) void k_gemm_mfma(const TIN* __restrict__ A,
                                                   const uint4* __restrict__ Wf,
                                                   ushort_t* __restrict__ Out) {
  int t = threadIdx.x;
  int wv = t >> 6, lane = t & 63;
  int row16 = lane & 15, chunk = lane >> 4;  // chunk 0..3
  int row0 = blockIdx.x * 64 + wv * 16;
  int arow = row0 + row16;
  if (arow >= N_NODES) arow = 0;  // stores are guarded
  bf16x8 afrag[4];
  if constexpr (sizeof(TIN) == 4) {  // fp32 input
    const float* Ar = A + (size_t)arow * D + chunk * 8;
#pragma unroll
    for (int s = 0; s < 4; ++s) {
      float4 lo = *(const float4*)(Ar + s * 32);
      float4 hi = *(const float4*)(Ar + s * 32 + 4);
      uint4 u;
      u.x = f2bf(lo.x) | (f2bf(lo.y) << 16);
      u.y = f2bf(lo.z) | (f2bf(lo.w) << 16);
      u.z = f2bf(hi.x) | (f2bf(hi.y) << 16);
      u.w = f2bf(hi.z) | (f2bf(hi.w) << 16);
      afrag[s] = *(bf16x8*)&u;
    }
  } else {  // bf16 input
    const ushort_t* Ar = A + (size_t)arow * D + chunk * 8;
#pragma unroll
    for (int s = 0; s < 4; ++s) afrag[s] = *(const bf16x8*)(Ar + s * 32);
  }
  f32x4 acc[8];
#pragma unroll
  for (int n = 0; n < 8; ++n) acc[n] = (f32x4){0.f, 0.f, 0.f, 0.f};
  const bf16x8* Wb = (const bf16x8*)Wf;
#pragma unroll
  for (int n = 0; n < 8; ++n) {
#pragma unroll
    for (int s = 0; s < 4; ++s) {
      bf16x8 b = Wb[(n * 4 + s) * 64 + lane];
      acc[n] = __builtin_amdgcn_mfma_f32_16x16x32_bf16(afrag[s], b, acc[n], 0, 0, 0);
    }
  }
  int crow0 = row0 + chunk * 4;  // C/D: col=lane&15, row=(lane>>4)*4+reg
#pragma unroll
  for (int n = 0; n < 8; ++n) {
#pragma unroll
    for (int j = 0; j < 4; ++j) {
      int r = crow0 + j;
      if (r < N_NODES)
        Out[(size_t)r * D + n * 16 + row16] = (ushort_t)f2bf(acc[n][j]);
    }
  }
}

// ---- agg layer1: one wave per node; relu(agg + b1) -> bf16 ----
__global__ __launch_bounds__(256) void k_agg_relu(const ushort_t* __restrict__ h,
                                                  const int2* __restrict__ csr,
                                                  const int* __restrict__ offs,
                                                  const float* __restrict__ dinv,
                                                  const float* __restrict__ bias,
                                                  ushort_t* __restrict__ obf) {
  int wv = threadIdx.x >> 6;
  int lane = threadIdx.x & 63;
  int node = blockIdx.x * 4 + wv;
  int grp = lane >> 4;   // 0..3: which edge of the chunk
  int gl = lane & 15;    // lane in group
  int d0 = gl * 8;       // dims [d0, d0+8)
  int beg = offs[node], end = offs[node + 1];
  float acc[8] = {0.f, 0.f, 0.f, 0.f, 0.f, 0.f, 0.f, 0.f};
  for (int base = beg + grp; base < end; base += 4) {
    int2 e = csr[base];  // all 16 lanes in group: same addr (broadcast)
    float w = __int_as_float(e.y);
    uint4 v = *(const uint4*)(h + (size_t)e.x * D + d0);
    acc[0] = fmaf(w, bf2f(v.x & 0xffffu), acc[0]);
    acc[1] = fmaf(w, bf2f(v.x >> 16), acc[1]);
    acc[2] = fmaf(w, bf2f(v.y & 0xffffu), acc[2]);
    acc[3] = fmaf(w, bf2f(v.y >> 16), acc[3]);
    acc[4] = fmaf(w, bf2f(v.z & 0xffffu), acc[4]);
    acc[5] = fmaf(w, bf2f(v.z >> 16), acc[5]);
    acc[6] = fmaf(w, bf2f(v.w & 0xffffu), acc[6]);
    acc[7] = fmaf(w, bf2f(v.w >> 16), acc[7]);
  }
#pragma unroll
  for (int m = 16; m <= 32; m <<= 1) {
#pragma unroll
    for (int i = 0; i < 8; ++i) acc[i] += __shfl_xor(acc[i], m);
  }
  if (grp == 0) {
    float dn = dinv[node];
    float wsl = dn * dn;
    uint4 v = *(const uint4*)(h + (size_t)node * D + d0);
    acc[0] = fmaf(wsl, bf2f(v.x & 0xffffu), acc[0]);
    acc[1] = fmaf(wsl, bf2f(v.x >> 16), acc[1]);
    acc[2] = fmaf(wsl, bf2f(v.y & 0xffffu), acc[2]);
    acc[3] = fmaf(wsl, bf2f(v.y >> 16), acc[3]);
    acc[4] = fmaf(wsl, bf2f(v.z & 0xffffu), acc[4]);
    acc[5] = fmaf(wsl, bf2f(v.z >> 16), acc[5]);
    acc[6] = fmaf(wsl, bf2f(v.w & 0xffffu), acc[6]);
    acc[7] = fmaf(wsl, bf2f(v.w >> 16), acc[7]);
    float4 blo = *(const float4*)(bias + d0);
    float4 bhi = *(const float4*)(bias + d0 + 4);
    acc[0] += blo.x; acc[1] += blo.y; acc[2] += blo.z; acc[3] += blo.w;
    acc[4] += bhi.x; acc[5] += bhi.y; acc[6] += bhi.z; acc[7] += bhi.w;
#pragma unroll
    for (int i = 0; i < 8; ++i) acc[i] = fmaxf(acc[i], 0.f);
    uint4 o;
    o.x = f2bf(acc[0]) | (f2bf(acc[1]) << 16);
    o.y = f2bf(acc[2]) | (f2bf(acc[3]) << 16);
    o.z = f2bf(acc[4]) | (f2bf(acc[5]) << 16);
    o.w = f2bf(acc[6]) | (f2bf(acc[7]) << 16);
    *(uint4*)(obf + (size_t)node * D + d0) = o;
  }
}

// ---- agg layer2 fused with mean-pool: sums[g] += agg(node)/cnt[g] ----
__global__ __launch_bounds__(256) void k_agg_pool(const ushort_t* __restrict__ h,
                                                   const int2* __restrict__ csr,
                                                   const int* __restrict__ offs,
                                                   const float* __restrict__ dinv,
                                                   const int* __restrict__ batch,
                                                   const float* __restrict__ rcnts,
                                                   float* __restrict__ sums) {
  __shared__ float pool[128];
  int t = threadIdx.x;
  int wv = t >> 6, lane = t & 63;
  int grp = lane >> 4, gl = lane & 15;
  int d0 = gl * 8;
  int node0 = blockIdx.x * 16;  // N_NODES % 16 == 0
  int g0 = batch[node0];
  if (t < 128) pool[t] = 0.f;
  __syncthreads();
  float pacc[8] = {0.f, 0.f, 0.f, 0.f, 0.f, 0.f, 0.f, 0.f};
  for (int i = 0; i < 4; ++i) {
    int node = node0 + wv * 4 + i;
    int beg = offs[node], end = offs[node + 1];
    float acc[8] = {0.f, 0.f, 0.f, 0.f, 0.f, 0.f, 0.f, 0.f};
    for (int base = beg + grp; base < end; base += 4) {
      int2 e = csr[base];
      float w = __int_as_float(e.y);
      uint4 v = *(const uint4*)(h + (size_t)e.x * D + d0);
      acc[0] = fmaf(w, bf2f(v.x & 0xffffu), acc[0]);
      acc[1] = fmaf(w, bf2f(v.x >> 16), acc[1]);
      acc[2] = fmaf(w, bf2f(v.y & 0xffffu), acc[2]);
      acc[3] = fmaf(w, bf2f(v.y >> 16), acc[3]);
      acc[4] = fmaf(w, bf2f(v.z & 0xffffu), acc[4]);
      acc[5] = fmaf(w, bf2f(v.z >> 16), acc[5]);
      acc[6] = fmaf(w, bf2f(v.w & 0xffffu), acc[6]);
      acc[7] = fmaf(w, bf2f(v.w >> 16), acc[7]);
    }
#pragma unroll
    for (int m = 16; m <= 32; m <<= 1) {
#pragma unroll
      for (int k = 0; k < 8; ++k) acc[k] += __shfl_xor(acc[k], m);
    }
    if (grp == 0) {
      float dn = dinv[node];
      float wsl = dn * dn;
      uint4 v = *(const uint4*)(h + (size_t)node * D + d0);
      acc[0] = fmaf(wsl, bf2f(v.x & 0xffffu), acc[0]);
      acc[1] = fmaf(wsl, bf2f(v.x >> 16), acc[1]);
      acc[2] = fmaf(wsl, bf2f(v.y & 0xffffu), acc[2]);
      acc[3] = fmaf(wsl, bf2f(v.y >> 16), acc[3]);
      acc[4] = fmaf(wsl, bf2f(v.z & 0xffffu), acc[4]);
      acc[5] = fmaf(wsl, bf2f(v.z >> 16), acc[5]);
      acc[6] = fmaf(wsl, bf2f(v.w & 0xffffu), acc[6]);
      acc[7] = fmaf(wsl, bf2f(v.w >> 16), acc[7]);
      int g = batch[node];
      float rc = rcnts[g];
      if (g == g0) {
#pragma unroll
        for (int k = 0; k < 8; ++k) pacc[k] = fmaf(acc[k], rc, pacc[k]);
      } else {
#pragma unroll
        for (int k = 0; k < 8; ++k)
          atomicAdd(&sums[(size_t)g * D + d0 + k], acc[k] * rc);
      }
    }
  }
  if (grp == 0) {
#pragma unroll
    for (int k = 0; k < 8; ++k) atomicAdd(&pool[d0 + k], pacc[k]);
  }
  __syncthreads();
  if (t < 128) atomicAdd(&sums[(size_t)g0 * D + t], pool[t]);
}

// ---- mean(+b2) + final linear head ----
__global__ __launch_bounds__(128) void k_final(const float* __restrict__ sums,
                                               const float* __restrict__ b2,
                                               const float* __restrict__ Wc,
                                               const float* __restrict__ bc,
                                               float* __restrict__ out) {
  __shared__ float p[128];
  int g = blockIdx.x;
  int t = threadIdx.x;
  p[t] = sums[g * D + t] + b2[t];
  __syncthreads();
  if (t < N_CLASSES) {
    float acc = bc[t];
    for (int k = 0; k < D; ++k) acc = fmaf(p[k], Wc[k * N_CLASSES + t], acc);
    out[g * N_CLASSES + t] = acc;
  }
}

extern "C" void kernel_launch(void* const* d_in, const int* in_sizes, int n_in,
                              void* d_out, int out_size, void* d_ws, size_t ws_size,
                              hipStream_t stream) {
  const float* x = (const float*)d_in[0];
  const int* ei = (const int*)d_in[1];
  const int* batch = (const int*)d_in[2];
  const float* W1 = (const float*)d_in[3];
  const float* b1 = (const float*)d_in[4];
  const float* W2 = (const float*)d_in[5];
  const float* b2 = (const float*)d_in[6];
  const float* Wc = (const float*)d_in[7];
  const float* bc = (const float*)d_in[8];
  float* out = (float*)d_out;

  char* ws = (char*)d_ws;
  size_t off = 0;
  auto alloc = [&](size_t bytes) -> void* {
    void* p = (void*)(ws + off);
    off += (bytes + 255) & ~(size_t)255;
    return p;
  };
  // zero-init region: deg, sums contiguous at the front
  int* deg = (int*)alloc((size_t)N_NODES * 4);
  float* sums = (float*)alloc((size_t)N_GRAPHS * D * 4);
  size_t zero_bytes = off;
  int* offs = (int*)alloc((size_t)(N_NODES + 1) * 4);
  float* dinv = (float*)alloc((size_t)N_NODES * 4);
  float* rcnts = (float*)alloc((size_t)N_GRAPHS * 4);
  int* bsum = (int*)alloc((size_t)NB_SCAN * 4);
  int* bpre = (int*)alloc((size_t)NB_SCAN * 4);
  uchar_t* rank = (uchar_t*)alloc((size_t)N_EDGES);
  uint4* W1f = (uint4*)alloc((size_t)2048 * 16);
  uint4* W2f = (uint4*)alloc((size_t)2048 * 16);
  int2* csr = (int2*)alloc((size_t)N_EDGES * 8);
  ushort_t* hbuf = (ushort_t*)alloc((size_t)N_NODES * D * 2);  // conv in (bf16)
  ushort_t* x2 = (ushort_t*)alloc((size_t)N_NODES * D * 2);    // relu(conv1) bf16

  hipMemsetAsync(ws, 0, zero_bytes, stream);

  k_pre<<<(N_EDGES + 255) / 256, 256, 0, stream>>>(ei, deg, rank);
  k_wprep<<<16, 256, 0, stream>>>(W1, W2, W1f, W2f);
  k_bsum<<<NB_SCAN, 256, 0, stream>>>(deg, dinv, bsum);
  k_spart<<<1, 256, 0, stream>>>(bsum, batch, bpre, offs, rcnts);
  k_fill<<<NB_SCAN, 256, 0, stream>>>(deg, bpre, offs);
  k_csr<<<(N_EDGES + 255) / 256, 256, 0, stream>>>(ei, dinv, offs, rank, csr);

  k_gemm_mfma<float><<<(N_NODES + 63) / 64, 256, 0, stream>>>(x, W1f, hbuf);
  k_agg_relu<<<N_NODES / 4, 256, 0, stream>>>(hbuf, csr, offs, dinv, b1, x2);
  k_gemm_mfma<ushort_t><<<(N_NODES + 63) / 64, 256, 0, stream>>>(x2, W2f, hbuf);
  k_agg_pool<<<N_NODES / 16, 256, 0, stream>>>(hbuf, csr, offs, dinv, batch, rcnts, sums);

  k_final<<<N_GRAPHS, 128, 0, stream>>>(sums, b2, Wc, bc, out);
}